// Round 17
// baseline (177.326 us; speedup 1.0000x reference)
//
#include <hip/hip_runtime.h>
#include <hip/hip_bf16.h>

// MPNN: B=8, N=36, H=64, STEPS=5
// messages[b,j,k] = (1/N^2) * sum_{i,l} edge[b,i,j,k,l] * nodes[b,i,l]
// nodes = GRUCell(messages, nodes) * mask, repeated STEPS times.
//
// Structure (5 launches): NO bf16 copy. All 5 steps are the same fused
// f32 einsum+GRU kernel. The 170 MB f32 edge is then the ONLY large buffer
// -> fully Infinity-Cache resident (170 < 256 MB, poison fill doesn't
// allocate) across steps and graph replays. Avoids the measured ~2.8 TB/s
// mixed-stream wall caused by edge(170)+ebf(85) = 255 MB thrashing L3.

#define BB 8
#define NN 36
#define HH 64
#define WAVES 4          // waves per block
#define IPW (NN / WAVES) // 9 i's per wave
#define NBJ (BB * NN)    // 288 blocks
#define INVN2 (1.0f / (float)(NN * NN))

// GRU cell for one node; lane t computes output dim t from LDS-staged
// message (ms) and hidden (hs) vectors. Rows t, t+64, t+128 of w_ih/w_hh.
__device__ __forceinline__ float gru_lane(
    const float* __restrict__ ms, const float* __restrict__ hs, int t,
    const float* __restrict__ w_ih, const float* __restrict__ w_hh,
    const float* __restrict__ b_ih, const float* __restrict__ b_hh)
{
    float gi0 = b_ih[t], gi1 = b_ih[HH + t], gi2 = b_ih[2 * HH + t];
    float gh0 = b_hh[t], gh1 = b_hh[HH + t], gh2 = b_hh[2 * HH + t];

    const float4* __restrict__ wi0 = (const float4*)(w_ih + (0 * HH + t) * HH);
    const float4* __restrict__ wi1 = (const float4*)(w_ih + (1 * HH + t) * HH);
    const float4* __restrict__ wi2 = (const float4*)(w_ih + (2 * HH + t) * HH);
    const float4* __restrict__ wh0 = (const float4*)(w_hh + (0 * HH + t) * HH);
    const float4* __restrict__ wh1 = (const float4*)(w_hh + (1 * HH + t) * HH);
    const float4* __restrict__ wh2 = (const float4*)(w_hh + (2 * HH + t) * HH);

    #pragma unroll
    for (int k4 = 0; k4 < HH / 4; ++k4) {
        const float4 mv = *(const float4*)&ms[k4 * 4];
        const float4 hv = *(const float4*)&hs[k4 * 4];
        float4 a;
        a = wi0[k4]; gi0 += a.x * mv.x + a.y * mv.y + a.z * mv.z + a.w * mv.w;
        a = wi1[k4]; gi1 += a.x * mv.x + a.y * mv.y + a.z * mv.z + a.w * mv.w;
        a = wi2[k4]; gi2 += a.x * mv.x + a.y * mv.y + a.z * mv.z + a.w * mv.w;
        a = wh0[k4]; gh0 += a.x * hv.x + a.y * hv.y + a.z * hv.z + a.w * hv.w;
        a = wh1[k4]; gh1 += a.x * hv.x + a.y * hv.y + a.z * hv.z + a.w * hv.w;
        a = wh2[k4]; gh2 += a.x * hv.x + a.y * hv.y + a.z * hv.z + a.w * hv.w;
    }
    const float r = 1.f / (1.f + expf(-(gi0 + gh0)));
    const float z = 1.f / (1.f + expf(-(gi1 + gh1)));
    const float n = tanhf(gi2 + r * gh2);
    return (1.f - z) * n + z * hs[t];
}

// ---------------------------------------------------------------------------
// Fused step: einsum on L3-resident f32 edge + in-block GRU.
// grid = 288 blocks x 256 threads (4 waves); block owns node (b,j);
// wave w streams i = 9w..9w+8. Per i: 16 float4 chunks c = it*64+lane
// (coalesced 1KB/instr): k = 4*it + lane/16, l4 = lane&15 (lane covers
// l = 4*l4..4*l4+3). acc[16] static -> registers. 4-stage butterfly over
// low 4 lane bits sums the 16 l-segments; lane (p=lane&15, gq=lane>>4)
// holds k = 4p+gq -> LDS part[w][k]. Reduce 4 wave-partials + GRU inline.
// ---------------------------------------------------------------------------
__global__ __launch_bounds__(256, 2) void step_f32(
    const float* __restrict__ edge,
    const float* __restrict__ nodes_in,
    const float* __restrict__ mask,
    const float* __restrict__ w_ih, const float* __restrict__ w_hh,
    const float* __restrict__ b_ih, const float* __restrict__ b_hh,
    float* __restrict__ nodes_out)
{
    const int tid  = threadIdx.x;
    const int lane = tid & 63;
    const int wv   = tid >> 6;
    const int bj = blockIdx.x;
    const int j  = bj % NN;
    const int b  = bj / NN;

    __shared__ float part[WAVES][HH];
    __shared__ float ms[HH];
    __shared__ float hs[HH];

    const int l4 = lane & 15;

    float acc[16];
    #pragma unroll
    for (int it = 0; it < 16; ++it) acc[it] = 0.f;

    for (int ii = 0; ii < IPW; ++ii) {
        const int i = wv * IPW + ii;
        const float4 v = *(const float4*)(nodes_in + (b * NN + i) * HH + l4 * 4);
        const size_t blkElem = (size_t)((b * NN + i) * NN + j) * (HH * HH);
        const float4* __restrict__ Wb = (const float4*)(edge + blkElem);
        #pragma unroll
        for (int it = 0; it < 16; ++it) {
            const float4 w = Wb[it * 64 + lane];
            acc[it] = fmaf(w.x, v.x, acc[it]);
            acc[it] = fmaf(w.y, v.y, acc[it]);
            acc[it] = fmaf(w.z, v.z, acc[it]);
            acc[it] = fmaf(w.w, v.w, acc[it]);
        }
    }

    // reduce the 16 l-segments across each 16-lane group (low 4 lane bits)
    #pragma unroll
    for (int m = 1; m < 16; m <<= 1) {
        #pragma unroll
        for (int it = 0; it < 16; ++it)
            acc[it] += __shfl_xor(acc[it], m, 64);
    }

    // lane (gq = lane>>4, p = lane&15) holds k = 4*p + gq = acc[p]
    const int p  = lane & 15;
    const int gq = lane >> 4;
    float outv = acc[0];
    #pragma unroll
    for (int t = 1; t < 16; ++t) outv = (p == t) ? acc[t] : outv;
    part[wv][4 * p + gq] = outv;

    __syncthreads();

    if (tid < HH) {
        const float m = part[0][tid] + part[1][tid] + part[2][tid] + part[3][tid];
        ms[tid] = m * INVN2;
        hs[tid] = nodes_in[bj * HH + tid];
    }
    __syncthreads();

    if (tid < HH) {
        const float o = gru_lane(ms, hs, tid, w_ih, w_hh, b_ih, b_hh);
        nodes_out[bj * HH + tid] = o * mask[bj];
    }
}

extern "C" void kernel_launch(void* const* d_in, const int* in_sizes, int n_in,
                              void* d_out, int out_size, void* d_ws, size_t ws_size,
                              hipStream_t stream) {
    const float* edge   = (const float*)d_in[0];
    const float* nodes0 = (const float*)d_in[1];
    const float* mask   = (const float*)d_in[2];
    const float* w_ih   = (const float*)d_in[3];
    const float* w_hh   = (const float*)d_in[4];
    const float* b_ih   = (const float*)d_in[5];
    const float* b_hh   = (const float*)d_in[6];
    float* out = (float*)d_out;

    float* ws = (float*)d_ws;
    const int nodes_elems = BB * NN * HH;          // 18432
    float* nodesA = ws;
    float* nodesB = ws + nodes_elems;

    // 5 identical fused steps; edge stays L3-resident throughout.
    step_f32<<<NBJ, 256, 0, stream>>>(edge, nodes0, mask,
                                      w_ih, w_hh, b_ih, b_hh, nodesA);
    step_f32<<<NBJ, 256, 0, stream>>>(edge, nodesA, mask,
                                      w_ih, w_hh, b_ih, b_hh, nodesB);
    step_f32<<<NBJ, 256, 0, stream>>>(edge, nodesB, mask,
                                      w_ih, w_hh, b_ih, b_hh, nodesA);
    step_f32<<<NBJ, 256, 0, stream>>>(edge, nodesA, mask,
                                      w_ih, w_hh, b_ih, b_hh, nodesB);
    step_f32<<<NBJ, 256, 0, stream>>>(edge, nodesB, mask,
                                      w_ih, w_hh, b_ih, b_hh, out);
}